// Round 3
// baseline (651.619 us; speedup 1.0000x reference)
//
#include <hip/hip_runtime.h>
#include <stdint.h>

#define BATCH 4096

__device__ __forceinline__ int sgn8(float v) {
    return (v > 0.f) ? 1 : ((v < 0.f) ? -1 : 0);
}

// ---------------------------------------------------------------------------
// Reorder + sign weights: out[((coct*32+cin)*9+tap)*8+ci] =
//   sign(w[((coct*8+ci)*32+cin)*9+tap])   (w is OIHW [32][32][3][3])
// ---------------------------------------------------------------------------
__global__ void k_signw(const float* __restrict__ w, float* __restrict__ o) {
    int i = blockIdx.x * 256 + threadIdx.x;
    if (i >= 9216) return;
    int ci = i & 7;
    int r = i >> 3;
    int tap = r % 9;
    int cc = r / 9;
    int cin = cc & 31;
    int coct = cc >> 5;
    float v = w[((coct * 8 + ci) * 32 + cin) * 9 + tap];
    o[i] = (v > 0.f) ? 1.f : ((v < 0.f) ? -1.f : 0.f);
}

// ---------------------------------------------------------------------------
// conv0: fp32 1->32ch, 3x3 pad1 on 28x28, then maxpool2 -> p0 [B][32][14][14]
// One block per image; x staged in LDS with zero halo (30x30).
// ---------------------------------------------------------------------------
__global__ __launch_bounds__(256) void k_conv0(const float* __restrict__ x,
                                               const float* __restrict__ w0,
                                               float* __restrict__ p0) {
    __shared__ float xs[900];   // 30x30 halo
    __shared__ float wl[288];
    int n = blockIdx.x, t = threadIdx.x;
    for (int i = t; i < 900; i += 256) xs[i] = 0.f;
    __syncthreads();
    for (int i = t; i < 784; i += 256) {
        int y = i / 28, xx = i - y * 28;
        xs[(y + 1) * 30 + xx + 1] = x[n * 784 + i];
    }
    for (int i = t; i < 288; i += 256) wl[i] = w0[i];
    __syncthreads();
    for (int idx = t; idx < 6272; idx += 256) {
        int c = idx / 196;
        int pix = idx - c * 196;
        int py = pix / 14, px = pix - py * 14;
        const float* wp = &wl[c * 9];
        float a[4][4];
        #pragma unroll
        for (int r = 0; r < 4; ++r) {
            const float2* ar = (const float2*)&xs[(2 * py + r) * 30 + 2 * px];
            float2 lo = ar[0], hi = ar[1];
            a[r][0] = lo.x; a[r][1] = lo.y; a[r][2] = hi.x; a[r][3] = hi.y;
        }
        float m = -3.4e38f;
        #pragma unroll
        for (int dy = 0; dy < 2; ++dy)
        #pragma unroll
        for (int dx = 0; dx < 2; ++dx) {
            float s = 0.f;
            #pragma unroll
            for (int ky = 0; ky < 3; ++ky)
            #pragma unroll
            for (int kx = 0; kx < 3; ++kx)
                s = fmaf(a[dy + ky][dx + kx], wp[ky * 3 + kx], s);
            m = fmaxf(m, s);
        }
        p0[n * 6272 + idx] = m;
    }
}

// ---------------------------------------------------------------------------
// Per-channel sum/sumsq over p [N][32][HW], double accumulation.
// grid (32, G). DETERMINISTIC: partial per block -> part[c*G+by] (sum) and
// part[32*G + c*G+by] (sumsq); no atomics.
// ---------------------------------------------------------------------------
__global__ __launch_bounds__(256) void k_stats(const float* __restrict__ p, int HW,
                                               int n_per_block, int N,
                                               double* __restrict__ part, int G) {
    int c = blockIdx.x;
    int by = blockIdx.y;
    int n0 = by * n_per_block;
    int t = threadIdx.x;
    double s = 0.0, q = 0.0;
    int n1 = min(n0 + n_per_block, N);
    for (int n = n0; n < n1; ++n) {
        const float* base = p + (n * 32 + c) * HW;
        for (int i = t; i < HW; i += 256) {
            double v = (double)base[i];
            s += v; q += v * v;
        }
    }
    #pragma unroll
    for (int o = 32; o > 0; o >>= 1) { s += __shfl_down(s, o); q += __shfl_down(q, o); }
    __shared__ double rs[4], rq[4];
    int w = t >> 6, l = t & 63;
    if (l == 0) { rs[w] = s; rq[w] = q; }
    __syncthreads();
    if (t == 0) {
        s = rs[0] + rs[1] + rs[2] + rs[3];
        q = rq[0] + rq[1] + rq[2] + rq[3];
        part[c * G + by] = s;
        part[32 * G + c * G + by] = q;
    }
}

// ---------------------------------------------------------------------------
// finalize: fixed-order sum of partials (deterministic), double math.
// scale = g/sqrt(var+eps); shift = b - mean*scale
// ---------------------------------------------------------------------------
__global__ void k_finalize(const double* __restrict__ part, int G,
                           const float* __restrict__ g, const float* __restrict__ b,
                           double inv_count, float* __restrict__ ss) {
    int c = threadIdx.x;
    if (c < 32) {
        double s = 0.0, q = 0.0;
        for (int i = 0; i < G; ++i) { s += part[c * G + i]; q += part[32 * G + c * G + i]; }
        double mean = s * inv_count;
        double var = q * inv_count - mean * mean;
        double sc = (double)g[c] / sqrt(var + 1e-5);
        ss[c] = (float)sc;
        ss[32 + c] = (float)((double)b[c] - mean * sc);
    }
}

// ---------------------------------------------------------------------------
// bn0 apply + sign(int8) + maxpool2 -> hp0.  Thread per (n,c,row-pair).
// ---------------------------------------------------------------------------
__global__ __launch_bounds__(256) void k_bn0(const float* __restrict__ p0,
                                             const float* __restrict__ ss,
                                             int8_t* __restrict__ s0,
                                             float* __restrict__ hp0) {
    int tid = blockIdx.x * 256 + threadIdx.x;   // exactly B*32*7
    int yp = tid % 7;
    int nc = tid / 7;
    int c = nc & 31;
    float sc = ss[c], sh = ss[32 + c];
    const float4* r4 = (const float4*)(p0 + nc * 196 + 28 * yp);  // 16B aligned
    float hv[28];
    #pragma unroll
    for (int j = 0; j < 7; ++j) {
        float4 v = r4[j];
        hv[4 * j]     = fmaf(sc, v.x, sh);
        hv[4 * j + 1] = fmaf(sc, v.y, sh);
        hv[4 * j + 2] = fmaf(sc, v.z, sh);
        hv[4 * j + 3] = fmaf(sc, v.w, sh);
    }
    uint32_t* sp = (uint32_t*)(s0 + nc * 196 + 28 * yp);
    #pragma unroll
    for (int j = 0; j < 7; ++j) {
        uint32_t u = 0;
        #pragma unroll
        for (int k = 0; k < 4; ++k)
            u |= ((uint32_t)(uint8_t)(int8_t)sgn8(hv[4 * j + k])) << (8 * k);
        sp[j] = u;
    }
    #pragma unroll
    for (int px = 0; px < 7; ++px) {
        float m = fmaxf(fmaxf(hv[2 * px], hv[2 * px + 1]),
                        fmaxf(hv[14 + 2 * px], hv[14 + 2 * px + 1]));
        hp0[nc * 49 + yp * 7 + px] = m;
    }
}

// ---------------------------------------------------------------------------
// conv1: binary 32->32ch 3x3 pad1 on 14x14 + maxpool2 -> p1 [B][32][7][7]
// One block per image. Acts in LDS [32][16][16] (zero halo). Thread computes
// 2x2 pool window x 8 couts = 32 accumulators. Weights via L1 (broadcast).
// ---------------------------------------------------------------------------
__global__ __launch_bounds__(256) void k_conv1(const int8_t* __restrict__ s0,
                                               const float* __restrict__ w1s,
                                               float* __restrict__ p1) {
    __shared__ float act[32 * 256];   // 32 KB
    int n = blockIdx.x, t = threadIdx.x;
    for (int i = t; i < 8192; i += 256) act[i] = 0.f;
    __syncthreads();
    for (int i = t; i < 6272; i += 256) {
        int cin = i / 196;
        int pix = i - cin * 196;
        int y = pix / 14, xx = pix - y * 14;
        act[cin * 256 + (y + 1) * 16 + xx + 1] = (float)s0[n * 6272 + i];
    }
    __syncthreads();
    if (t < 196) {
        int coct = t / 49;
        int pix = t - coct * 49;
        int py = pix / 7, px = pix - py * 7;
        float acc[4][8];
        #pragma unroll
        for (int q = 0; q < 4; ++q)
            #pragma unroll
            for (int ci = 0; ci < 8; ++ci) acc[q][ci] = 0.f;
        const float* wb = w1s + coct * 2304;
        const float* ab0 = act + 2 * py * 16 + 2 * px;
        for (int cin = 0; cin < 32; ++cin) {
            float a[4][4];
            const float* ab = ab0 + cin * 256;
            #pragma unroll
            for (int rr = 0; rr < 4; ++rr) {
                const float2* ar = (const float2*)(ab + rr * 16);  // 8B aligned
                float2 lo = ar[0], hi = ar[1];
                a[rr][0] = lo.x; a[rr][1] = lo.y; a[rr][2] = hi.x; a[rr][3] = hi.y;
            }
            const float* wc = wb + cin * 72;
            #pragma unroll
            for (int ky = 0; ky < 3; ++ky)
            #pragma unroll
            for (int kx = 0; kx < 3; ++kx) {
                const float4* wp = (const float4*)(wc + (ky * 3 + kx) * 8);
                float4 wlo = wp[0], whi = wp[1];
                float wv[8] = {wlo.x, wlo.y, wlo.z, wlo.w, whi.x, whi.y, whi.z, whi.w};
                #pragma unroll
                for (int dy = 0; dy < 2; ++dy)
                #pragma unroll
                for (int dx = 0; dx < 2; ++dx) {
                    float av = a[dy + ky][dx + kx];
                    #pragma unroll
                    for (int ci = 0; ci < 8; ++ci)
                        acc[dy * 2 + dx][ci] = fmaf(av, wv[ci], acc[dy * 2 + dx][ci]);
                }
            }
        }
        #pragma unroll
        for (int ci = 0; ci < 8; ++ci) {
            float m = fmaxf(fmaxf(acc[0][ci], acc[1][ci]),
                            fmaxf(acc[2][ci], acc[3][ci]));
            p1[(n * 32 + coct * 8 + ci) * 49 + pix] = m;
        }
    }
}

// ---------------------------------------------------------------------------
// bn1 apply + shortcut add + sign + maxpool2(7->3) -> s1 (packed), hp1.
// Thread per (n,c) plane.  s1 stored as 13 uints (52 B) per plane.
// ---------------------------------------------------------------------------
__global__ __launch_bounds__(256) void k_bn1(const float* __restrict__ p1,
                                             const float* __restrict__ hp0,
                                             const float* __restrict__ ss,
                                             uint32_t* __restrict__ s1,
                                             float* __restrict__ hp1) {
    int nc = blockIdx.x * 256 + threadIdx.x;   // exactly B*32
    int c = nc & 31;
    float sc = ss[64 + c], sh = ss[96 + c];
    const float* pb = p1 + nc * 49;
    const float* hb = hp0 + nc * 49;
    float h[49];
    #pragma unroll
    for (int i = 0; i < 49; ++i) h[i] = fmaf(sc, pb[i], sh) + hb[i];
    uint32_t* sp = s1 + nc * 13;
    #pragma unroll
    for (int j = 0; j < 13; ++j) {
        uint32_t u = 0;
        #pragma unroll
        for (int k = 0; k < 4; ++k) {
            int f = 4 * j + k;
            int sv = (f < 49) ? sgn8(h[f]) : 0;
            u |= ((uint32_t)(uint8_t)(int8_t)sv) << (8 * k);
        }
        sp[j] = u;
    }
    #pragma unroll
    for (int r = 0; r < 3; ++r)
    #pragma unroll
    for (int q = 0; q < 3; ++q) {
        float m = fmaxf(fmaxf(h[2 * r * 7 + 2 * q], h[2 * r * 7 + 2 * q + 1]),
                        fmaxf(h[(2 * r + 1) * 7 + 2 * q], h[(2 * r + 1) * 7 + 2 * q + 1]));
        hp1[nc * 9 + r * 3 + q] = m;
    }
}

// ---------------------------------------------------------------------------
// conv2: binary 32->32ch 3x3 pad1 on 7x7 + maxpool2(->3x3) -> p2 [B][32][9]
// 5 images per block; LDS [5][32][9][10] (zero halo, col pad for alignment).
// Only the 6x6 conv pixels feeding the floor-pool are computed.
// ---------------------------------------------------------------------------
__global__ __launch_bounds__(256) void k_conv2(const uint32_t* __restrict__ s1,
                                               const float* __restrict__ w2s,
                                               float* __restrict__ p2, int N) {
    __shared__ float act[5 * 32 * 90];   // 57.6 KB
    int n0 = blockIdx.x * 5;
    int t = threadIdx.x;
    for (int i = t; i < 5 * 32 * 90; i += 256) act[i] = 0.f;
    __syncthreads();
    for (int i = t; i < 5 * 416; i += 256) {
        int img = i / 416;
        int rem = i - img * 416;
        int cin = rem / 13;
        int j = rem - cin * 13;
        int n = n0 + img;
        if (n < N) {
            uint32_t u = s1[n * 416 + cin * 13 + j];
            #pragma unroll
            for (int k = 0; k < 4; ++k) {
                int f = 4 * j + k;
                if (f < 49) {
                    int y = f / 7, xx = f - y * 7;
                    act[(img * 32 + cin) * 90 + (y + 1) * 10 + xx + 1] =
                        (float)(int8_t)((u >> (8 * k)) & 0xFF);
                }
            }
        }
    }
    __syncthreads();
    if (t < 180) {
        int img = t / 36;
        int r = t - img * 36;
        int coct = r / 9;
        int pix = r - coct * 9;
        int py = pix / 3, px = pix - py * 3;
        int n = n0 + img;
        float acc[4][8];
        #pragma unroll
        for (int q = 0; q < 4; ++q)
            #pragma unroll
            for (int ci = 0; ci < 8; ++ci) acc[q][ci] = 0.f;
        const float* wb = w2s + coct * 2304;
        const float* ab0 = act + img * 2880 + 2 * py * 10 + 2 * px;
        for (int cin = 0; cin < 32; ++cin) {
            float a[4][4];
            const float* ab = ab0 + cin * 90;
            #pragma unroll
            for (int rr = 0; rr < 4; ++rr) {
                const float2* ar = (const float2*)(ab + rr * 10);
                float2 lo = ar[0], hi = ar[1];
                a[rr][0] = lo.x; a[rr][1] = lo.y; a[rr][2] = hi.x; a[rr][3] = hi.y;
            }
            const float* wc = wb + cin * 72;
            #pragma unroll
            for (int ky = 0; ky < 3; ++ky)
            #pragma unroll
            for (int kx = 0; kx < 3; ++kx) {
                const float4* wp = (const float4*)(wc + (ky * 3 + kx) * 8);
                float4 wlo = wp[0], whi = wp[1];
                float wv[8] = {wlo.x, wlo.y, wlo.z, wlo.w, whi.x, whi.y, whi.z, whi.w};
                #pragma unroll
                for (int dy = 0; dy < 2; ++dy)
                #pragma unroll
                for (int dx = 0; dx < 2; ++dx) {
                    float av = a[dy + ky][dx + kx];
                    #pragma unroll
                    for (int ci = 0; ci < 8; ++ci)
                        acc[dy * 2 + dx][ci] = fmaf(av, wv[ci], acc[dy * 2 + dx][ci]);
                }
            }
        }
        if (n < N) {
            #pragma unroll
            for (int ci = 0; ci < 8; ++ci) {
                float m = fmaxf(fmaxf(acc[0][ci], acc[1][ci]),
                                fmaxf(acc[2][ci], acc[3][ci]));
                p2[(n * 32 + coct * 8 + ci) * 9 + pix] = m;
            }
        }
    }
}

// ---------------------------------------------------------------------------
// FC: out[n,k] = sum_j (bn2(p2)+hp1)[n,j] * fw[k,j] + fb[k].  Wave per image.
// ---------------------------------------------------------------------------
__global__ __launch_bounds__(256) void k_fc(const float* __restrict__ p2,
                                            const float* __restrict__ hp1,
                                            const float* __restrict__ ss,
                                            const float* __restrict__ fw,
                                            const float* __restrict__ fb,
                                            float* __restrict__ outv) {
    int wv = threadIdx.x >> 6, l = threadIdx.x & 63;
    int n = blockIdx.x * 4 + wv;
    float acc[10];
    #pragma unroll
    for (int k = 0; k < 10; ++k) acc[k] = 0.f;
    #pragma unroll
    for (int i = 0; i < 5; ++i) {
        int j = l + 64 * i;
        if (j < 288) {
            int c = j / 9;
            float h = fmaf(ss[128 + c], p2[n * 288 + j], ss[160 + c]) + hp1[n * 288 + j];
            #pragma unroll
            for (int k = 0; k < 10; ++k)
                acc[k] = fmaf(h, fw[k * 288 + j], acc[k]);
        }
    }
    #pragma unroll
    for (int k = 0; k < 10; ++k) {
        float s = acc[k];
        #pragma unroll
        for (int o = 32; o > 0; o >>= 1) s += __shfl_down(s, o);
        if (l == 0) outv[n * 10 + k] = s + fb[k];
    }
}

// ---------------------------------------------------------------------------
// Workspace layout (bytes). Total ~154.2 MB. p1/s1/hp1/p2 alias the dead p0.
// BN partials (all stages) alias the HEAD OF s0 — s0 is outside p0's extent
// and is dead during every stats->finalize window:
//   stage 0: stats/finalize run BEFORE bn0 writes s0 (stream order)
//   stage 1: conv1 consumed s0 before stats1 writes
//   stage 2: s0 fully dead
//   ss      @ 1024       768   (scale0,shift0,scale1,shift1,scale2,shift2)
//   w1s     @ 2048       36864
//   w2s     @ 38912      36864
//   p0      @ 76800      102760448   (live k_conv0 .. k_bn0)
//   p1      @ 76800      25690112    (alias; live k_conv1 .. k_bn1)
//   s1      @ 25766912   6815744     (alias dead p0)
//   hp1     @ 32582656   4718592     (alias dead p0; NOT aliased by partials)
//   p2      @ 37301248   4718592     (alias dead p0)
//   s0      @ 102837248  25690112    (partials alias its head, 32 KB)
//   hp0     @ 128527360  25690112    (end 154217472)
// ---------------------------------------------------------------------------
extern "C" void kernel_launch(void* const* d_in, const int* in_sizes, int n_in,
                              void* d_out, int out_size, void* d_ws, size_t ws_size,
                              hipStream_t stream) {
    (void)in_sizes; (void)n_in; (void)out_size; (void)ws_size;
    const float* x  = (const float*)d_in[0];
    const float* w0 = (const float*)d_in[1];
    const float* g0 = (const float*)d_in[2];
    const float* b0 = (const float*)d_in[3];
    const float* w1 = (const float*)d_in[4];
    const float* g1 = (const float*)d_in[5];
    const float* b1 = (const float*)d_in[6];
    const float* w2 = (const float*)d_in[7];
    const float* g2 = (const float*)d_in[8];
    const float* b2 = (const float*)d_in[9];
    const float* fw = (const float*)d_in[10];
    const float* fb = (const float*)d_in[11];
    float* outv = (float*)d_out;
    char* ws = (char*)d_ws;

    float*    ss    = (float*)(ws + 1024);
    float*    w1s   = (float*)(ws + 2048);
    float*    w2s   = (float*)(ws + 38912);
    float*    p0    = (float*)(ws + 76800);
    float*    p1    = (float*)(ws + 76800);
    uint32_t* s1    = (uint32_t*)(ws + 25766912);
    float*    hp1   = (float*)(ws + 32582656);
    float*    p2    = (float*)(ws + 37301248);
    int8_t*   s0    = (int8_t*)(ws + 102837248);
    float*    hp0   = (float*)(ws + 128527360);
    double*   part  = (double*)(ws + 102837248);  // alias s0 head (dead in window)

    k_signw<<<36, 256, 0, stream>>>(w1, w1s);
    k_signw<<<36, 256, 0, stream>>>(w2, w2s);

    k_conv0<<<BATCH, 256, 0, stream>>>(x, w0, p0);
    k_stats<<<dim3(32, 64), 256, 0, stream>>>(p0, 196, 64, BATCH, part, 64);
    k_finalize<<<1, 64, 0, stream>>>(part, 64, g0, b0, 1.0 / (BATCH * 196.0), ss);
    k_bn0<<<(BATCH * 32 * 7) / 256, 256, 0, stream>>>(p0, ss, s0, hp0);

    k_conv1<<<BATCH, 256, 0, stream>>>(s0, w1s, p1);
    k_stats<<<dim3(32, 64), 256, 0, stream>>>(p1, 49, 64, BATCH, part, 64);
    k_finalize<<<1, 64, 0, stream>>>(part, 64, g1, b1, 1.0 / (BATCH * 49.0), ss + 64);
    k_bn1<<<(BATCH * 32) / 256, 256, 0, stream>>>(p1, hp0, ss, s1, hp1);

    k_conv2<<<(BATCH + 4) / 5, 256, 0, stream>>>(s1, w2s, p2, BATCH);
    k_stats<<<dim3(32, 32), 256, 0, stream>>>(p2, 9, 128, BATCH, part, 32);
    k_finalize<<<1, 64, 0, stream>>>(part, 32, g2, b2, 1.0 / (BATCH * 9.0), ss + 128);

    k_fc<<<BATCH / 4, 256, 0, stream>>>(p2, hp1, ss, fw, fb, outv);
}

// Round 4
// 487.510 us; speedup vs baseline: 1.3366x; 1.3366x over previous
//
#include <hip/hip_runtime.h>
#include <stdint.h>

#define BATCH 4096

typedef float v16f __attribute__((ext_vector_type(16)));
typedef short v8s  __attribute__((ext_vector_type(8)));

__device__ __forceinline__ int sgn8(float v) {
    return (v > 0.f) ? 1 : ((v < 0.f) ? -1 : 0);
}

// ---------------------------------------------------------------------------
// w1 sign -> bf16 MFMA B-fragment layout:
// o[tp*1024 + kh*512 + q*256 + n*8 + j] = sign(w1[n][kh*16+q*8+j][tp]) as bf16
// (lane q*32+n loads 16B at ((tp*2+kh)*2+q)*512 + n*16)
// ---------------------------------------------------------------------------
__global__ void k_signw1(const float* __restrict__ w, uint16_t* __restrict__ o) {
    int i = blockIdx.x * 256 + threadIdx.x;
    if (i >= 9216) return;
    int j = i & 7, n = (i >> 3) & 31, q = (i >> 8) & 1, kh = (i >> 9) & 1, tp = i >> 10;
    int cin = kh * 16 + q * 8 + j;
    float v = w[(n * 32 + cin) * 9 + tp];
    o[i] = (v > 0.f) ? 0x3F80 : ((v < 0.f) ? 0xBF80 : 0);
}

// ---------------------------------------------------------------------------
// w2 sign in fp32 for the (unchanged) direct conv2:
// out[((coct*32+cin)*9+tap)*8+ci] = sign(w[((coct*8+ci)*32+cin)*9+tap])
// ---------------------------------------------------------------------------
__global__ void k_signw(const float* __restrict__ w, float* __restrict__ o) {
    int i = blockIdx.x * 256 + threadIdx.x;
    if (i >= 9216) return;
    int ci = i & 7;
    int r = i >> 3;
    int tap = r % 9;
    int cc = r / 9;
    int cin = cc & 31;
    int coct = cc >> 5;
    float v = w[((coct * 8 + ci) * 32 + cin) * 9 + tap];
    o[i] = (v > 0.f) ? 1.f : ((v < 0.f) ? -1.f : 0.f);
}

// ---------------------------------------------------------------------------
// conv0: fp32 1->32ch, 3x3 pad1 on 28x28, then maxpool2 -> p0 [B][32][14][14]
// ---------------------------------------------------------------------------
__global__ __launch_bounds__(256) void k_conv0(const float* __restrict__ x,
                                               const float* __restrict__ w0,
                                               float* __restrict__ p0) {
    __shared__ float xs[900];   // 30x30 halo
    __shared__ float wl[288];
    int n = blockIdx.x, t = threadIdx.x;
    for (int i = t; i < 900; i += 256) xs[i] = 0.f;
    __syncthreads();
    for (int i = t; i < 784; i += 256) {
        int y = i / 28, xx = i - y * 28;
        xs[(y + 1) * 30 + xx + 1] = x[n * 784 + i];
    }
    for (int i = t; i < 288; i += 256) wl[i] = w0[i];
    __syncthreads();
    for (int idx = t; idx < 6272; idx += 256) {
        int c = idx / 196;
        int pix = idx - c * 196;
        int py = pix / 14, px = pix - py * 14;
        const float* wp = &wl[c * 9];
        float a[4][4];
        #pragma unroll
        for (int r = 0; r < 4; ++r) {
            const float2* ar = (const float2*)&xs[(2 * py + r) * 30 + 2 * px];
            float2 lo = ar[0], hi = ar[1];
            a[r][0] = lo.x; a[r][1] = lo.y; a[r][2] = hi.x; a[r][3] = hi.y;
        }
        float m = -3.4e38f;
        #pragma unroll
        for (int dy = 0; dy < 2; ++dy)
        #pragma unroll
        for (int dx = 0; dx < 2; ++dx) {
            float s = 0.f;
            #pragma unroll
            for (int ky = 0; ky < 3; ++ky)
            #pragma unroll
            for (int kx = 0; kx < 3; ++kx)
                s = fmaf(a[dy + ky][dx + kx], wp[ky * 3 + kx], s);
            m = fmaxf(m, s);
        }
        p0[n * 6272 + idx] = m;
    }
}

// ---------------------------------------------------------------------------
// Per-channel sum/sumsq over NCHW p [N][32][HW], double acc, deterministic.
// ---------------------------------------------------------------------------
__global__ __launch_bounds__(256) void k_stats(const float* __restrict__ p, int HW,
                                               int n_per_block, int N,
                                               double* __restrict__ part, int G) {
    int c = blockIdx.x;
    int by = blockIdx.y;
    int n0 = by * n_per_block;
    int t = threadIdx.x;
    double s = 0.0, q = 0.0;
    int n1 = min(n0 + n_per_block, N);
    for (int n = n0; n < n1; ++n) {
        const float* base = p + (n * 32 + c) * HW;
        for (int i = t; i < HW; i += 256) {
            double v = (double)base[i];
            s += v; q += v * v;
        }
    }
    #pragma unroll
    for (int o = 32; o > 0; o >>= 1) { s += __shfl_down(s, o); q += __shfl_down(q, o); }
    __shared__ double rs[4], rq[4];
    int w = t >> 6, l = t & 63;
    if (l == 0) { rs[w] = s; rq[w] = q; }
    __syncthreads();
    if (t == 0) {
        s = rs[0] + rs[1] + rs[2] + rs[3];
        q = rq[0] + rq[1] + rq[2] + rq[3];
        part[c * G + by] = s;
        part[32 * G + c * G + by] = q;
    }
}

// ---------------------------------------------------------------------------
// Per-channel stats over NHWC p1 [N][49][32]. 64 blocks x 64 images.
// Deterministic fixed-order reduction.
// ---------------------------------------------------------------------------
__global__ __launch_bounds__(256) void k_stats1(const float* __restrict__ p1,
                                                double* __restrict__ part) {
    int b = blockIdx.x;
    int t = threadIdx.x;
    int c = t & 31, g = t >> 5;
    const float* base = p1 + (size_t)b * 64 * 1568;
    double s = 0.0, q = 0.0;
    for (int row = g; row < 64 * 49; row += 8) {
        double v = (double)base[row * 32 + c];
        s += v; q += v * v;
    }
    __shared__ double rs[8][32], rq[8][32];
    rs[g][c] = s; rq[g][c] = q;
    __syncthreads();
    if (t < 32) {
        double S = 0.0, Q = 0.0;
        for (int i = 0; i < 8; ++i) { S += rs[i][t]; Q += rq[i][t]; }
        part[t * 64 + b] = S;
        part[32 * 64 + t * 64 + b] = Q;
    }
}

// ---------------------------------------------------------------------------
// finalize: fixed-order sum of partials (deterministic), double math.
// ---------------------------------------------------------------------------
__global__ void k_finalize(const double* __restrict__ part, int G,
                           const float* __restrict__ g, const float* __restrict__ b,
                           double inv_count, float* __restrict__ ss) {
    int c = threadIdx.x;
    if (c < 32) {
        double s = 0.0, q = 0.0;
        for (int i = 0; i < G; ++i) { s += part[c * G + i]; q += part[32 * G + c * G + i]; }
        double mean = s * inv_count;
        double var = q * inv_count - mean * mean;
        double sc = (double)g[c] / sqrt(var + 1e-5);
        ss[c] = (float)sc;
        ss[32 + c] = (float)((double)b[c] - mean * sc);
    }
}

// ---------------------------------------------------------------------------
// bn0: block per image. p0 NCHW staged in LDS; writes s0 NHWC int8
// [n][196][32] and hp0 NHWC fp32 [n][49][32] (pool AFTER BN).
// ---------------------------------------------------------------------------
__global__ __launch_bounds__(256) void k_bn0(const float* __restrict__ p0,
                                             const float* __restrict__ ss,
                                             int8_t* __restrict__ s0,
                                             float* __restrict__ hp0) {
    __shared__ float P[6272];
    int n = blockIdx.x, t = threadIdx.x;
    const float* src = p0 + n * 6272;
    for (int i = t; i < 6272; i += 256) P[i] = src[i];
    __syncthreads();
    if (t < 196) {
        int p = t;
        uint32_t pk[8];
        #pragma unroll
        for (int cg = 0; cg < 8; ++cg) {
            uint32_t u = 0;
            #pragma unroll
            for (int k = 0; k < 4; ++k) {
                int c = cg * 4 + k;
                float v = fmaf(ss[c], P[c * 196 + p], ss[32 + c]);
                u |= ((uint32_t)(uint8_t)(int8_t)sgn8(v)) << (8 * k);
            }
            pk[cg] = u;
        }
        uint4* dst = (uint4*)(s0 + (size_t)n * 6272 + p * 32);
        uint4 v0; v0.x = pk[0]; v0.y = pk[1]; v0.z = pk[2]; v0.w = pk[3];
        uint4 v1; v1.x = pk[4]; v1.y = pk[5]; v1.z = pk[6]; v1.w = pk[7];
        dst[0] = v0; dst[1] = v1;

        int pw = t >> 2, oct = t & 3;           // 49 pw x 4 octs = 196
        int py = pw / 7, px = pw - py * 7;
        float out[8];
        #pragma unroll
        for (int k = 0; k < 8; ++k) {
            int c = oct * 8 + k;
            float sc = ss[c], sh = ss[32 + c];
            const float* B = &P[c * 196];
            float a0 = fmaf(sc, B[(2 * py) * 14 + 2 * px], sh);
            float a1 = fmaf(sc, B[(2 * py) * 14 + 2 * px + 1], sh);
            float a2 = fmaf(sc, B[(2 * py + 1) * 14 + 2 * px], sh);
            float a3 = fmaf(sc, B[(2 * py + 1) * 14 + 2 * px + 1], sh);
            out[k] = fmaxf(fmaxf(a0, a1), fmaxf(a2, a3));
        }
        float4* hd = (float4*)(hp0 + ((size_t)n * 49 + pw) * 32 + oct * 8);
        float4 h0; h0.x = out[0]; h0.y = out[1]; h0.z = out[2]; h0.w = out[3];
        float4 h1; h1.x = out[4]; h1.y = out[5]; h1.z = out[6]; h1.w = out[7];
        hd[0] = h0; hd[1] = h1;
    }
}

// ---------------------------------------------------------------------------
// conv1 via bf16 MFMA implicit GEMM. 4 images/block (one per wave).
// LDS act per image: [16][16 halo][32ch] bf16 with 16B-granule XOR swizzle.
// M-rows = 4*pool_window + quadrant -> pool happens in-register on C/D regs.
// 7 M-tiles x (9 taps x 2 K-halves) MFMA 32x32x16. p1 out NHWC [n][49][32].
// ---------------------------------------------------------------------------
__global__ __launch_bounds__(256) void k_conv1m(const int8_t* __restrict__ s0,
                                                const uint16_t* __restrict__ w1f,
                                                float* __restrict__ p1) {
    __shared__ uint32_t lds[16384];   // 64 KB: 4 images x 256 pixels x 16 dwords
    int t = threadIdx.x;
    int n0 = blockIdx.x * 4;
    // zero halo border pixels (full 64B rows -> swizzle-agnostic)
    if (t < 240) {
        int img = t / 60, e = t % 60;
        int yh, xh;
        if (e < 16)      { yh = 0;      xh = e; }
        else if (e < 32) { yh = 15;     xh = e - 16; }
        else if (e < 46) { yh = e - 31; xh = 0; }
        else             { yh = e - 45; xh = 15; }
        uint32_t* d = &lds[img * 4096 + (yh * 16 + xh) * 16];
        uint4 z; z.x = z.y = z.z = z.w = 0u;
        ((uint4*)d)[0] = z; ((uint4*)d)[1] = z; ((uint4*)d)[2] = z; ((uint4*)d)[3] = z;
    }
    // load B-fragments (global, L2-broadcast): 18 frags x 16B per lane
    int lane = t & 63, wv = t >> 6;
    int q = lane >> 5, ncol = lane & 31;
    v8s wfr[18];
    #pragma unroll
    for (int f = 0; f < 18; ++f)
        wfr[f] = *(const v8s*)(w1f + (f * 2 + q) * 256 + ncol * 8);
    // stage 4 images: int8 NHWC -> bf16 swizzled LDS
    for (int i = t; i < 6272; i += 256) {
        int img = i / 1568, r = i - img * 1568;
        int pimg = r >> 3, dp = r & 7;
        int iy = pimg / 14, ix = pimg - iy * 14;
        int p = (iy + 1) * 16 + ix + 1;
        uint32_t u = ((const uint32_t*)s0)[(size_t)(n0 + img) * 1568 + r];
        uint32_t b0 = u & 0xFF, b1 = (u >> 8) & 0xFF, b2 = (u >> 16) & 0xFF, b3 = u >> 24;
        uint32_t h0 = b0 ? (0x3F80u | ((b0 & 0x80u) << 8)) : 0u;
        uint32_t h1 = b1 ? (0x3F80u | ((b1 & 0x80u) << 8)) : 0u;
        uint32_t h2 = b2 ? (0x3F80u | ((b2 & 0x80u) << 8)) : 0u;
        uint32_t h3 = b3 ? (0x3F80u | ((b3 & 0x80u) << 8)) : 0u;
        int g = dp >> 1;
        int gs = g ^ (p & 3);
        int idx = img * 4096 + p * 16 + (gs << 2) + ((dp & 1) << 1);
        lds[idx] = h0 | (h1 << 16);
        lds[idx + 1] = h2 | (h3 << 16);
    }
    __syncthreads();
    int n = n0 + wv;
    int ibase = wv * 4096;
    int m = lane & 31;
    int quad = m & 3, pwl = m >> 2;
    int dy = quad >> 1, dx = quad & 1;
    for (int tile = 0; tile < 7; ++tile) {
        int pw = tile * 8 + pwl;
        int pwc = min(pw, 48);
        int py = pwc / 7, px = pwc - py * 7;
        int pbase = (2 * py + dy) * 16 + 2 * px + dx;
        v16f acc;
        #pragma unroll
        for (int i = 0; i < 16; ++i) acc[i] = 0.f;
        #pragma unroll
        for (int tp = 0; tp < 9; ++tp) {
            int p = pbase + (tp / 3) * 16 + (tp % 3);
            int psw = p & 3;
            #pragma unroll
            for (int kh = 0; kh < 2; ++kh) {
                int g = kh * 2 + q;
                int idx = ibase + p * 16 + ((g ^ psw) << 2);
                v8s a = *(const v8s*)&lds[idx];
                acc = __builtin_amdgcn_mfma_f32_32x32x16_bf16(a, wfr[tp * 2 + kh], acc, 0, 0, 0);
            }
        }
        // C/D rows: (reg&3) + 8*(reg>>2) + 4*q -> in-register 2x2 maxpool
        #pragma unroll
        for (int g4 = 0; g4 < 4; ++g4) {
            float mx = fmaxf(fmaxf(acc[4 * g4], acc[4 * g4 + 1]),
                             fmaxf(acc[4 * g4 + 2], acc[4 * g4 + 3]));
            int pwo = tile * 8 + 2 * g4 + q;
            if (pwo < 49)
                p1[((size_t)n * 49 + pwo) * 32 + ncol] = mx;
        }
    }
}

// ---------------------------------------------------------------------------
// bn1: block per image. h = bn1(p1) + hp0 (both NHWC) in LDS; emits
// s1 NCHW-packed (for conv2) and hp1 NCHW [n][c][9] (for FC).
// ---------------------------------------------------------------------------
__global__ __launch_bounds__(256) void k_bn1(const float* __restrict__ p1,
                                             const float* __restrict__ hp0,
                                             const float* __restrict__ ss,
                                             uint32_t* __restrict__ s1,
                                             float* __restrict__ hp1) {
    __shared__ float H[1568];
    int n = blockIdx.x, t = threadIdx.x;
    const float* P = p1 + (size_t)n * 1568;
    const float* Hp = hp0 + (size_t)n * 1568;
    for (int i = t; i < 1568; i += 256) {
        int c = i & 31;
        H[i] = fmaf(ss[64 + c], P[i], ss[96 + c]) + Hp[i];
    }
    __syncthreads();
    if (t < 32) {
        int c = t;
        uint32_t* sp = s1 + n * 416 + c * 13;
        for (int j = 0; j < 13; ++j) {
            uint32_t u = 0;
            #pragma unroll
            for (int k = 0; k < 4; ++k) {
                int f = 4 * j + k;
                int sv = (f < 49) ? sgn8(H[f * 32 + c]) : 0;
                u |= ((uint32_t)(uint8_t)(int8_t)sv) << (8 * k);
            }
            sp[j] = u;
        }
    }
    for (int jj = t; jj < 288; jj += 256) {
        int c = jj / 9, pix = jj - c * 9;
        int r = pix / 3, qq = pix - r * 3;
        float a0 = H[((2 * r) * 7 + 2 * qq) * 32 + c];
        float a1 = H[((2 * r) * 7 + 2 * qq + 1) * 32 + c];
        float a2 = H[((2 * r + 1) * 7 + 2 * qq) * 32 + c];
        float a3 = H[((2 * r + 1) * 7 + 2 * qq + 1) * 32 + c];
        hp1[n * 288 + c * 9 + pix] = fmaxf(fmaxf(a0, a1), fmaxf(a2, a3));
    }
}

// ---------------------------------------------------------------------------
// conv2: binary 32->32ch 3x3 pad1 on 7x7 + maxpool2(->3x3) -> p2 [B][32][9]
// (unchanged direct kernel; rewrite candidate next round)
// ---------------------------------------------------------------------------
__global__ __launch_bounds__(256) void k_conv2(const uint32_t* __restrict__ s1,
                                               const float* __restrict__ w2s,
                                               float* __restrict__ p2, int N) {
    __shared__ float act[5 * 32 * 90];   // 57.6 KB
    int n0 = blockIdx.x * 5;
    int t = threadIdx.x;
    for (int i = t; i < 5 * 32 * 90; i += 256) act[i] = 0.f;
    __syncthreads();
    for (int i = t; i < 5 * 416; i += 256) {
        int img = i / 416;
        int rem = i - img * 416;
        int cin = rem / 13;
        int j = rem - cin * 13;
        int n = n0 + img;
        if (n < N) {
            uint32_t u = s1[n * 416 + cin * 13 + j];
            #pragma unroll
            for (int k = 0; k < 4; ++k) {
                int f = 4 * j + k;
                if (f < 49) {
                    int y = f / 7, xx = f - y * 7;
                    act[(img * 32 + cin) * 90 + (y + 1) * 10 + xx + 1] =
                        (float)(int8_t)((u >> (8 * k)) & 0xFF);
                }
            }
        }
    }
    __syncthreads();
    if (t < 180) {
        int img = t / 36;
        int r = t - img * 36;
        int coct = r / 9;
        int pix = r - coct * 9;
        int py = pix / 3, px = pix - py * 3;
        int n = n0 + img;
        float acc[4][8];
        #pragma unroll
        for (int qd = 0; qd < 4; ++qd)
            #pragma unroll
            for (int ci = 0; ci < 8; ++ci) acc[qd][ci] = 0.f;
        const float* wb = w2s + coct * 2304;
        const float* ab0 = act + img * 2880 + 2 * py * 10 + 2 * px;
        for (int cin = 0; cin < 32; ++cin) {
            float a[4][4];
            const float* ab = ab0 + cin * 90;
            #pragma unroll
            for (int rr = 0; rr < 4; ++rr) {
                const float2* ar = (const float2*)(ab + rr * 10);
                float2 lo = ar[0], hi = ar[1];
                a[rr][0] = lo.x; a[rr][1] = lo.y; a[rr][2] = hi.x; a[rr][3] = hi.y;
            }
            const float* wc = wb + cin * 72;
            #pragma unroll
            for (int ky = 0; ky < 3; ++ky)
            #pragma unroll
            for (int kx = 0; kx < 3; ++kx) {
                const float4* wp = (const float4*)(wc + (ky * 3 + kx) * 8);
                float4 wlo = wp[0], whi = wp[1];
                float wv[8] = {wlo.x, wlo.y, wlo.z, wlo.w, whi.x, whi.y, whi.z, whi.w};
                #pragma unroll
                for (int dy = 0; dy < 2; ++dy)
                #pragma unroll
                for (int dx = 0; dx < 2; ++dx) {
                    float av = a[dy + ky][dx + kx];
                    #pragma unroll
                    for (int ci = 0; ci < 8; ++ci)
                        acc[dy * 2 + dx][ci] = fmaf(av, wv[ci], acc[dy * 2 + dx][ci]);
                }
            }
        }
        if (n < N) {
            #pragma unroll
            for (int ci = 0; ci < 8; ++ci) {
                float m = fmaxf(fmaxf(acc[0][ci], acc[1][ci]),
                                fmaxf(acc[2][ci], acc[3][ci]));
                p2[(n * 32 + coct * 8 + ci) * 9 + pix] = m;
            }
        }
    }
}

// ---------------------------------------------------------------------------
// FC: out[n,k] = sum_j (bn2(p2)+hp1)[n,j] * fw[k,j] + fb[k].  Wave per image.
// ---------------------------------------------------------------------------
__global__ __launch_bounds__(256) void k_fc(const float* __restrict__ p2,
                                            const float* __restrict__ hp1,
                                            const float* __restrict__ ss,
                                            const float* __restrict__ fw,
                                            const float* __restrict__ fb,
                                            float* __restrict__ outv) {
    int wv = threadIdx.x >> 6, l = threadIdx.x & 63;
    int n = blockIdx.x * 4 + wv;
    float acc[10];
    #pragma unroll
    for (int k = 0; k < 10; ++k) acc[k] = 0.f;
    #pragma unroll
    for (int i = 0; i < 5; ++i) {
        int j = l + 64 * i;
        if (j < 288) {
            int c = j / 9;
            float h = fmaf(ss[128 + c], p2[n * 288 + j], ss[160 + c]) + hp1[n * 288 + j];
            #pragma unroll
            for (int k = 0; k < 10; ++k)
                acc[k] = fmaf(h, fw[k * 288 + j], acc[k]);
        }
    }
    #pragma unroll
    for (int k = 0; k < 10; ++k) {
        float s = acc[k];
        #pragma unroll
        for (int o = 32; o > 0; o >>= 1) s += __shfl_down(s, o);
        if (l == 0) outv[n * 10 + k] = s + fb[k];
    }
}

// ---------------------------------------------------------------------------
// Workspace layout (bytes), ~154.2 MB. Same offsets as R3; p1/s1/hp1/p2
// alias dead p0; BN partials alias s0 head (dead in every stats window).
//   ss   @1024  768 | w1f @2048 18432(bf16) | w2s @38912 36864
//   p0   @76800 102760448 | p1(NHWC) @76800 25690112
//   s1   @25766912 6815744 | hp1 @32582656 4718592 | p2 @37301248 4718592
//   s0(NHWC int8) @102837248 25690112 (part aliases head, 32KB)
//   hp0(NHWC)     @128527360 25690112
// ---------------------------------------------------------------------------
extern "C" void kernel_launch(void* const* d_in, const int* in_sizes, int n_in,
                              void* d_out, int out_size, void* d_ws, size_t ws_size,
                              hipStream_t stream) {
    (void)in_sizes; (void)n_in; (void)out_size; (void)ws_size;
    const float* x  = (const float*)d_in[0];
    const float* w0 = (const float*)d_in[1];
    const float* g0 = (const float*)d_in[2];
    const float* b0 = (const float*)d_in[3];
    const float* w1 = (const float*)d_in[4];
    const float* g1 = (const float*)d_in[5];
    const float* b1 = (const float*)d_in[6];
    const float* w2 = (const float*)d_in[7];
    const float* g2 = (const float*)d_in[8];
    const float* b2 = (const float*)d_in[9];
    const float* fw = (const float*)d_in[10];
    const float* fb = (const float*)d_in[11];
    float* outv = (float*)d_out;
    char* ws = (char*)d_ws;

    float*     ss   = (float*)(ws + 1024);
    uint16_t*  w1f  = (uint16_t*)(ws + 2048);
    float*     w2s  = (float*)(ws + 38912);
    float*     p0   = (float*)(ws + 76800);
    float*     p1   = (float*)(ws + 76800);
    uint32_t*  s1   = (uint32_t*)(ws + 25766912);
    float*     hp1  = (float*)(ws + 32582656);
    float*     p2   = (float*)(ws + 37301248);
    int8_t*    s0   = (int8_t*)(ws + 102837248);
    float*     hp0  = (float*)(ws + 128527360);
    double*    part = (double*)(ws + 102837248);  // alias s0 head (dead in window)

    k_signw1<<<36, 256, 0, stream>>>(w1, w1f);
    k_signw<<<36, 256, 0, stream>>>(w2, w2s);

    k_conv0<<<BATCH, 256, 0, stream>>>(x, w0, p0);
    k_stats<<<dim3(32, 64), 256, 0, stream>>>(p0, 196, 64, BATCH, part, 64);
    k_finalize<<<1, 64, 0, stream>>>(part, 64, g0, b0, 1.0 / (BATCH * 196.0), ss);
    k_bn0<<<BATCH, 256, 0, stream>>>(p0, ss, s0, hp0);

    k_conv1m<<<BATCH / 4, 256, 0, stream>>>(s0, w1f, p1);
    k_stats1<<<64, 256, 0, stream>>>(p1, part);
    k_finalize<<<1, 64, 0, stream>>>(part, 64, g1, b1, 1.0 / (BATCH * 49.0), ss + 64);
    k_bn1<<<BATCH, 256, 0, stream>>>(p1, hp0, ss, s1, hp1);

    k_conv2<<<(BATCH + 4) / 5, 256, 0, stream>>>(s1, w2s, p2, BATCH);
    k_stats<<<dim3(32, 32), 256, 0, stream>>>(p2, 9, 128, BATCH, part, 32);
    k_finalize<<<1, 64, 0, stream>>>(part, 32, g2, b2, 1.0 / (BATCH * 9.0), ss + 128);

    k_fc<<<BATCH / 4, 256, 0, stream>>>(p2, hp1, ss, fw, fb, outv);
}

// Round 5
// 308.291 us; speedup vs baseline: 2.1136x; 1.5813x over previous
//
#include <hip/hip_runtime.h>
#include <stdint.h>

#define BATCH 4096

typedef float v16f __attribute__((ext_vector_type(16)));
typedef short v8s  __attribute__((ext_vector_type(8)));

__device__ __forceinline__ int sgn8(float v) {
    return (v > 0.f) ? 1 : ((v < 0.f) ? -1 : 0);
}

// ---------------------------------------------------------------------------
// w1 sign -> bf16 MFMA B-fragment layout:
// o[tp*1024 + kh*512 + q*256 + n*8 + j] = sign(w1[n][kh*16+q*8+j][tp]) as bf16
// ---------------------------------------------------------------------------
__global__ void k_signw1(const float* __restrict__ w, uint16_t* __restrict__ o) {
    int i = blockIdx.x * 256 + threadIdx.x;
    if (i >= 9216) return;
    int j = i & 7, n = (i >> 3) & 31, q = (i >> 8) & 1, kh = (i >> 9) & 1, tp = i >> 10;
    int cin = kh * 16 + q * 8 + j;
    float v = w[(n * 32 + cin) * 9 + tp];
    o[i] = (v > 0.f) ? 0x3F80 : ((v < 0.f) ? 0xBF80 : 0);
}

// ---------------------------------------------------------------------------
// w2 sign in fp32 for direct conv2:
// out[((coct*32+cin)*9+tap)*8+ci] = sign(w[((coct*8+ci)*32+cin)*9+tap])
// ---------------------------------------------------------------------------
__global__ void k_signw(const float* __restrict__ w, float* __restrict__ o) {
    int i = blockIdx.x * 256 + threadIdx.x;
    if (i >= 9216) return;
    int ci = i & 7;
    int r = i >> 3;
    int tap = r % 9;
    int cc = r / 9;
    int cin = cc & 31;
    int coct = cc >> 5;
    float v = w[((coct * 8 + ci) * 32 + cin) * 9 + tap];
    o[i] = (v > 0.f) ? 1.f : ((v < 0.f) ? -1.f : 0.f);
}

// ---------------------------------------------------------------------------
// conv0: fp32 1->32ch 3x3 pad1 on 28x28 + maxpool2 -> p0 [B][32][14][14],
// WITH fused per-channel double stats. Thread owns channel c=t>>3 (8 threads
// per channel), so per-thread (s,q) accumulators are per-channel; 8-way LDS
// reduce -> part0[n*32+c] / part0[G*32 + n*32+c], G=4096. Deterministic.
// ---------------------------------------------------------------------------
__global__ __launch_bounds__(256) void k_conv0(const float* __restrict__ x,
                                               const float* __restrict__ w0,
                                               float* __restrict__ p0,
                                               double* __restrict__ part0) {
    __shared__ float xs[900];   // 30x30 halo
    __shared__ float wl[288];
    __shared__ double rs[32][8], rq[32][8];
    int n = blockIdx.x, t = threadIdx.x;
    for (int i = t; i < 900; i += 256) xs[i] = 0.f;
    __syncthreads();
    for (int i = t; i < 784; i += 256) {
        int y = i / 28, xx = i - y * 28;
        xs[(y + 1) * 30 + xx + 1] = x[n * 784 + i];
    }
    for (int i = t; i < 288; i += 256) wl[i] = w0[i];
    __syncthreads();
    int c = t >> 3, j = t & 7;
    const float* wp = &wl[c * 9];
    double s = 0.0, q = 0.0;
    for (int pix = j; pix < 196; pix += 8) {
        int py = pix / 14, px = pix - py * 14;
        float a[4][4];
        #pragma unroll
        for (int r = 0; r < 4; ++r) {
            const float2* ar = (const float2*)&xs[(2 * py + r) * 30 + 2 * px];
            float2 lo = ar[0], hi = ar[1];
            a[r][0] = lo.x; a[r][1] = lo.y; a[r][2] = hi.x; a[r][3] = hi.y;
        }
        float m = -3.4e38f;
        #pragma unroll
        for (int dy = 0; dy < 2; ++dy)
        #pragma unroll
        for (int dx = 0; dx < 2; ++dx) {
            float sum = 0.f;
            #pragma unroll
            for (int ky = 0; ky < 3; ++ky)
            #pragma unroll
            for (int kx = 0; kx < 3; ++kx)
                sum = fmaf(a[dy + ky][dx + kx], wp[ky * 3 + kx], sum);
            m = fmaxf(m, sum);
        }
        p0[n * 6272 + c * 196 + pix] = m;
        double v = (double)m;
        s += v; q += v * v;
    }
    rs[c][j] = s; rq[c][j] = q;
    __syncthreads();
    if (t < 32) {
        double S = 0.0, Q = 0.0;
        #pragma unroll
        for (int i = 0; i < 8; ++i) { S += rs[t][i]; Q += rq[t][i]; }
        part0[n * 32 + t] = S;
        part0[4096 * 32 + n * 32 + t] = Q;
    }
}

// ---------------------------------------------------------------------------
// finalize: grid(32) x 256 threads. Block = channel. Fixed-order reduction
// of G partials (layout part[i*32+c]); double math; deterministic.
// ---------------------------------------------------------------------------
__global__ __launch_bounds__(256) void k_finalize(const double* __restrict__ part, int G,
                                                  const float* __restrict__ g,
                                                  const float* __restrict__ b,
                                                  double inv_count, float* __restrict__ ss) {
    int c = blockIdx.x, t = threadIdx.x;
    double s = 0.0, q = 0.0;
    for (int i = t; i < G; i += 256) {
        s += part[i * 32 + c];
        q += part[G * 32 + i * 32 + c];
    }
    #pragma unroll
    for (int o = 32; o > 0; o >>= 1) { s += __shfl_down(s, o); q += __shfl_down(q, o); }
    __shared__ double rs[4], rq[4];
    int w = t >> 6, l = t & 63;
    if (l == 0) { rs[w] = s; rq[w] = q; }
    __syncthreads();
    if (t == 0) {
        s = rs[0] + rs[1] + rs[2] + rs[3];
        q = rq[0] + rq[1] + rq[2] + rq[3];
        double mean = s * inv_count;
        double var = q * inv_count - mean * mean;
        double sc = (double)g[c] / sqrt(var + 1e-5);
        ss[c] = (float)sc;
        ss[32 + c] = (float)((double)b[c] - mean * sc);
    }
}

// ---------------------------------------------------------------------------
// bn0: block per image. p0 NCHW staged in LDS; writes s0 NHWC int8
// [n][196][32] and hp0 NHWC fp32 [n][49][32].
// ---------------------------------------------------------------------------
__global__ __launch_bounds__(256) void k_bn0(const float* __restrict__ p0,
                                             const float* __restrict__ ss,
                                             int8_t* __restrict__ s0,
                                             float* __restrict__ hp0) {
    __shared__ float P[6272];
    int n = blockIdx.x, t = threadIdx.x;
    const float* src = p0 + n * 6272;
    for (int i = t; i < 6272; i += 256) P[i] = src[i];
    __syncthreads();
    if (t < 196) {
        int p = t;
        uint32_t pk[8];
        #pragma unroll
        for (int cg = 0; cg < 8; ++cg) {
            uint32_t u = 0;
            #pragma unroll
            for (int k = 0; k < 4; ++k) {
                int c = cg * 4 + k;
                float v = fmaf(ss[c], P[c * 196 + p], ss[32 + c]);
                u |= ((uint32_t)(uint8_t)(int8_t)sgn8(v)) << (8 * k);
            }
            pk[cg] = u;
        }
        uint4* dst = (uint4*)(s0 + (size_t)n * 6272 + p * 32);
        uint4 v0; v0.x = pk[0]; v0.y = pk[1]; v0.z = pk[2]; v0.w = pk[3];
        uint4 v1; v1.x = pk[4]; v1.y = pk[5]; v1.z = pk[6]; v1.w = pk[7];
        dst[0] = v0; dst[1] = v1;

        int pw = t >> 2, oct = t & 3;           // 49 pw x 4 octs = 196
        int py = pw / 7, px = pw - py * 7;
        float out[8];
        #pragma unroll
        for (int k = 0; k < 8; ++k) {
            int c = oct * 8 + k;
            float sc = ss[c], sh = ss[32 + c];
            const float* B = &P[c * 196];
            float a0 = fmaf(sc, B[(2 * py) * 14 + 2 * px], sh);
            float a1 = fmaf(sc, B[(2 * py) * 14 + 2 * px + 1], sh);
            float a2 = fmaf(sc, B[(2 * py + 1) * 14 + 2 * px], sh);
            float a3 = fmaf(sc, B[(2 * py + 1) * 14 + 2 * px + 1], sh);
            out[k] = fmaxf(fmaxf(a0, a1), fmaxf(a2, a3));
        }
        float4* hd = (float4*)(hp0 + ((size_t)n * 49 + pw) * 32 + oct * 8);
        float4 h0; h0.x = out[0]; h0.y = out[1]; h0.z = out[2]; h0.w = out[3];
        float4 h1; h1.x = out[4]; h1.y = out[5]; h1.z = out[6]; h1.w = out[7];
        hd[0] = h0; hd[1] = h1;
    }
}

// ---------------------------------------------------------------------------
// conv1 bf16 MFMA implicit GEMM, 4 images/block, WITH fused stats.
// Lane's output channel is fixed (ncol=lane&31) -> per-lane double (s,q);
// after the MFMA loop the act LDS is dead, reuse it for the 8-way reduce
// -> part1[b*32+c] / part1[1024*32 + b*32+c], G=1024. Deterministic.
// ---------------------------------------------------------------------------
__global__ __launch_bounds__(256) void k_conv1m(const int8_t* __restrict__ s0,
                                                const uint16_t* __restrict__ w1f,
                                                float* __restrict__ p1,
                                                double* __restrict__ part1) {
    __shared__ uint32_t lds[16384];   // 64 KB: 4 images x 256 pixels x 16 dwords
    int t = threadIdx.x;
    int n0 = blockIdx.x * 4;
    if (t < 240) {
        int img = t / 60, e = t % 60;
        int yh, xh;
        if (e < 16)      { yh = 0;      xh = e; }
        else if (e < 32) { yh = 15;     xh = e - 16; }
        else if (e < 46) { yh = e - 31; xh = 0; }
        else             { yh = e - 45; xh = 15; }
        uint32_t* d = &lds[img * 4096 + (yh * 16 + xh) * 16];
        uint4 z; z.x = z.y = z.z = z.w = 0u;
        ((uint4*)d)[0] = z; ((uint4*)d)[1] = z; ((uint4*)d)[2] = z; ((uint4*)d)[3] = z;
    }
    int lane = t & 63, wv = t >> 6;
    int q = lane >> 5, ncol = lane & 31;
    v8s wfr[18];
    #pragma unroll
    for (int f = 0; f < 18; ++f)
        wfr[f] = *(const v8s*)(w1f + (f * 2 + q) * 256 + ncol * 8);
    for (int i = t; i < 6272; i += 256) {
        int img = i / 1568, r = i - img * 1568;
        int pimg = r >> 3, dp = r & 7;
        int iy = pimg / 14, ix = pimg - iy * 14;
        int p = (iy + 1) * 16 + ix + 1;
        uint32_t u = ((const uint32_t*)s0)[(size_t)(n0 + img) * 1568 + r];
        uint32_t b0 = u & 0xFF, b1 = (u >> 8) & 0xFF, b2 = (u >> 16) & 0xFF, b3 = u >> 24;
        uint32_t h0 = b0 ? (0x3F80u | ((b0 & 0x80u) << 8)) : 0u;
        uint32_t h1 = b1 ? (0x3F80u | ((b1 & 0x80u) << 8)) : 0u;
        uint32_t h2 = b2 ? (0x3F80u | ((b2 & 0x80u) << 8)) : 0u;
        uint32_t h3 = b3 ? (0x3F80u | ((b3 & 0x80u) << 8)) : 0u;
        int g = dp >> 1;
        int gs = g ^ (p & 3);
        int idx = img * 4096 + p * 16 + (gs << 2) + ((dp & 1) << 1);
        lds[idx] = h0 | (h1 << 16);
        lds[idx + 1] = h2 | (h3 << 16);
    }
    __syncthreads();
    int n = n0 + wv;
    int ibase = wv * 4096;
    int m = lane & 31;
    int quad = m & 3, pwl = m >> 2;
    int dy = quad >> 1, dx = quad & 1;
    double sAcc = 0.0, qAcc = 0.0;
    for (int tile = 0; tile < 7; ++tile) {
        int pw = tile * 8 + pwl;
        int pwc = min(pw, 48);
        int py = pwc / 7, px = pwc - py * 7;
        int pbase = (2 * py + dy) * 16 + 2 * px + dx;
        v16f acc;
        #pragma unroll
        for (int i = 0; i < 16; ++i) acc[i] = 0.f;
        #pragma unroll
        for (int tp = 0; tp < 9; ++tp) {
            int p = pbase + (tp / 3) * 16 + (tp % 3);
            int psw = p & 3;
            #pragma unroll
            for (int kh = 0; kh < 2; ++kh) {
                int g = kh * 2 + q;
                int idx = ibase + p * 16 + ((g ^ psw) << 2);
                v8s a = *(const v8s*)&lds[idx];
                acc = __builtin_amdgcn_mfma_f32_32x32x16_bf16(a, wfr[tp * 2 + kh], acc, 0, 0, 0);
            }
        }
        #pragma unroll
        for (int g4 = 0; g4 < 4; ++g4) {
            float mx = fmaxf(fmaxf(acc[4 * g4], acc[4 * g4 + 1]),
                             fmaxf(acc[4 * g4 + 2], acc[4 * g4 + 3]));
            int pwo = tile * 8 + 2 * g4 + q;
            if (pwo < 49) {
                p1[((size_t)n * 49 + pwo) * 32 + ncol] = mx;
                double v = (double)mx;
                sAcc += v; qAcc += v * v;
            }
        }
    }
    // fused stats reduce: act LDS is dead now
    __syncthreads();
    double* red = (double*)lds;   // 512 doubles used
    red[(wv * 2 + q) * 32 + ncol] = sAcc;
    red[256 + (wv * 2 + q) * 32 + ncol] = qAcc;
    __syncthreads();
    if (t < 32) {
        double S = 0.0, Q = 0.0;
        #pragma unroll
        for (int i = 0; i < 8; ++i) { S += red[i * 32 + t]; Q += red[256 + i * 32 + t]; }
        part1[blockIdx.x * 32 + t] = S;
        part1[1024 * 32 + blockIdx.x * 32 + t] = Q;
    }
}

// ---------------------------------------------------------------------------
// bn1: block per image. h = bn1(p1) + hp0 (both NHWC) in LDS; emits
// s1 NCHW-packed (for conv2) and hp1 NCHW [n][c][9] (for FC).
// ---------------------------------------------------------------------------
__global__ __launch_bounds__(256) void k_bn1(const float* __restrict__ p1,
                                             const float* __restrict__ hp0,
                                             const float* __restrict__ ss,
                                             uint32_t* __restrict__ s1,
                                             float* __restrict__ hp1) {
    __shared__ float H[1568];
    int n = blockIdx.x, t = threadIdx.x;
    const float* P = p1 + (size_t)n * 1568;
    const float* Hp = hp0 + (size_t)n * 1568;
    for (int i = t; i < 1568; i += 256) {
        int c = i & 31;
        H[i] = fmaf(ss[64 + c], P[i], ss[96 + c]) + Hp[i];
    }
    __syncthreads();
    if (t < 32) {
        int c = t;
        uint32_t* sp = s1 + n * 416 + c * 13;
        for (int j = 0; j < 13; ++j) {
            uint32_t u = 0;
            #pragma unroll
            for (int k = 0; k < 4; ++k) {
                int f = 4 * j + k;
                int sv = (f < 49) ? sgn8(H[f * 32 + c]) : 0;
                u |= ((uint32_t)(uint8_t)(int8_t)sv) << (8 * k);
            }
            sp[j] = u;
        }
    }
    for (int jj = t; jj < 288; jj += 256) {
        int c = jj / 9, pix = jj - c * 9;
        int r = pix / 3, qq = pix - r * 3;
        float a0 = H[((2 * r) * 7 + 2 * qq) * 32 + c];
        float a1 = H[((2 * r) * 7 + 2 * qq + 1) * 32 + c];
        float a2 = H[((2 * r + 1) * 7 + 2 * qq) * 32 + c];
        float a3 = H[((2 * r + 1) * 7 + 2 * qq + 1) * 32 + c];
        hp1[n * 288 + c * 9 + pix] = fmaxf(fmaxf(a0, a1), fmaxf(a2, a3));
    }
}

// ---------------------------------------------------------------------------
// conv2: binary 32->32ch 3x3 pad1 on 7x7 + maxpool2(->3x3) -> p2 [B][32][9]
// ---------------------------------------------------------------------------
__global__ __launch_bounds__(256) void k_conv2(const uint32_t* __restrict__ s1,
                                               const float* __restrict__ w2s,
                                               float* __restrict__ p2, int N) {
    __shared__ float act[5 * 32 * 90];   // 57.6 KB
    int n0 = blockIdx.x * 5;
    int t = threadIdx.x;
    for (int i = t; i < 5 * 32 * 90; i += 256) act[i] = 0.f;
    __syncthreads();
    for (int i = t; i < 5 * 416; i += 256) {
        int img = i / 416;
        int rem = i - img * 416;
        int cin = rem / 13;
        int j = rem - cin * 13;
        int n = n0 + img;
        if (n < N) {
            uint32_t u = s1[n * 416 + cin * 13 + j];
            #pragma unroll
            for (int k = 0; k < 4; ++k) {
                int f = 4 * j + k;
                if (f < 49) {
                    int y = f / 7, xx = f - y * 7;
                    act[(img * 32 + cin) * 90 + (y + 1) * 10 + xx + 1] =
                        (float)(int8_t)((u >> (8 * k)) & 0xFF);
                }
            }
        }
    }
    __syncthreads();
    if (t < 180) {
        int img = t / 36;
        int r = t - img * 36;
        int coct = r / 9;
        int pix = r - coct * 9;
        int py = pix / 3, px = pix - py * 3;
        int n = n0 + img;
        float acc[4][8];
        #pragma unroll
        for (int qd = 0; qd < 4; ++qd)
            #pragma unroll
            for (int ci = 0; ci < 8; ++ci) acc[qd][ci] = 0.f;
        const float* wb = w2s + coct * 2304;
        const float* ab0 = act + img * 2880 + 2 * py * 10 + 2 * px;
        for (int cin = 0; cin < 32; ++cin) {
            float a[4][4];
            const float* ab = ab0 + cin * 90;
            #pragma unroll
            for (int rr = 0; rr < 4; ++rr) {
                const float2* ar = (const float2*)(ab + rr * 10);
                float2 lo = ar[0], hi = ar[1];
                a[rr][0] = lo.x; a[rr][1] = lo.y; a[rr][2] = hi.x; a[rr][3] = hi.y;
            }
            const float* wc = wb + cin * 72;
            #pragma unroll
            for (int ky = 0; ky < 3; ++ky)
            #pragma unroll
            for (int kx = 0; kx < 3; ++kx) {
                const float4* wp = (const float4*)(wc + (ky * 3 + kx) * 8);
                float4 wlo = wp[0], whi = wp[1];
                float wv[8] = {wlo.x, wlo.y, wlo.z, wlo.w, whi.x, whi.y, whi.z, whi.w};
                #pragma unroll
                for (int dy = 0; dy < 2; ++dy)
                #pragma unroll
                for (int dx = 0; dx < 2; ++dx) {
                    float av = a[dy + ky][dx + kx];
                    #pragma unroll
                    for (int ci = 0; ci < 8; ++ci)
                        acc[dy * 2 + dx][ci] = fmaf(av, wv[ci], acc[dy * 2 + dx][ci]);
                }
            }
        }
        if (n < N) {
            #pragma unroll
            for (int ci = 0; ci < 8; ++ci) {
                float m = fmaxf(fmaxf(acc[0][ci], acc[1][ci]),
                                fmaxf(acc[2][ci], acc[3][ci]));
                p2[(n * 32 + coct * 8 + ci) * 9 + pix] = m;
            }
        }
    }
}

// ---------------------------------------------------------------------------
// stats2: p2 NCHW [N][32][9]. 256 blocks x 16 images; thread owns channel
// c=t>>3, j=t&7 -> all 256 threads active. part2[b*32+c], G=256.
// ---------------------------------------------------------------------------
__global__ __launch_bounds__(256) void k_stats2p(const float* __restrict__ p2,
                                                 double* __restrict__ part2) {
    int b = blockIdx.x, t = threadIdx.x;
    int c = t >> 3, j = t & 7;
    double s = 0.0, q = 0.0;
    const float* base = p2 + (size_t)b * 16 * 288;
    #pragma unroll 4
    for (int img = 0; img < 16; ++img) {
        const float* pl = base + img * 288 + c * 9;
        for (int jj = j; jj < 9; jj += 8) {
            double v = (double)pl[jj];
            s += v; q += v * v;
        }
    }
    __shared__ double rs[32][8], rq[32][8];
    rs[c][j] = s; rq[c][j] = q;
    __syncthreads();
    if (t < 32) {
        double S = 0.0, Q = 0.0;
        #pragma unroll
        for (int i = 0; i < 8; ++i) { S += rs[t][i]; Q += rq[t][i]; }
        part2[b * 32 + t] = S;
        part2[256 * 32 + b * 32 + t] = Q;
    }
}

// ---------------------------------------------------------------------------
// FC: out[n,k] = sum_j (bn2(p2)+hp1)[n,j] * fw[k,j] + fb[k].  Wave per image.
// ---------------------------------------------------------------------------
__global__ __launch_bounds__(256) void k_fc(const float* __restrict__ p2,
                                            const float* __restrict__ hp1,
                                            const float* __restrict__ ss,
                                            const float* __restrict__ fw,
                                            const float* __restrict__ fb,
                                            float* __restrict__ outv) {
    int wv = threadIdx.x >> 6, l = threadIdx.x & 63;
    int n = blockIdx.x * 4 + wv;
    float acc[10];
    #pragma unroll
    for (int k = 0; k < 10; ++k) acc[k] = 0.f;
    #pragma unroll
    for (int i = 0; i < 5; ++i) {
        int j = l + 64 * i;
        if (j < 288) {
            int c = j / 9;
            float h = fmaf(ss[128 + c], p2[n * 288 + j], ss[160 + c]) + hp1[n * 288 + j];
            #pragma unroll
            for (int k = 0; k < 10; ++k)
                acc[k] = fmaf(h, fw[k * 288 + j], acc[k]);
        }
    }
    #pragma unroll
    for (int k = 0; k < 10; ++k) {
        float s = acc[k];
        #pragma unroll
        for (int o = 32; o > 0; o >>= 1) s += __shfl_down(s, o);
        if (l == 0) outv[n * 10 + k] = s + fb[k];
    }
}

// ---------------------------------------------------------------------------
// Workspace layout (bytes), ~154.2 MB.
//   ss   @1024  768 | w1f @2048 18432(bf16) | w2s @38912 36864
//   p0   @76800 102760448 | p1(NHWC) @76800 25690112
//   s1   @25766912 | hp1 @32582656 | p2 @37301248 (all alias dead p0)
//   part1 @60000000 512KB  (dead mid-p0 zone during conv1m->finalize1;
//                           NOT s0 -- conv1m is still reading s0)
//   s0(NHWC int8) @102837248 25690112
//     part0 (2 MB, conv0->finalize0, before bn0 writes s0) aliases its head
//     part2 (128 KB, stats2->finalize2, s0 long dead) aliases its head
//   hp0(NHWC) @128527360 25690112
// ---------------------------------------------------------------------------
extern "C" void kernel_launch(void* const* d_in, const int* in_sizes, int n_in,
                              void* d_out, int out_size, void* d_ws, size_t ws_size,
                              hipStream_t stream) {
    (void)in_sizes; (void)n_in; (void)out_size; (void)ws_size;
    const float* x  = (const float*)d_in[0];
    const float* w0 = (const float*)d_in[1];
    const float* g0 = (const float*)d_in[2];
    const float* b0 = (const float*)d_in[3];
    const float* w1 = (const float*)d_in[4];
    const float* g1 = (const float*)d_in[5];
    const float* b1 = (const float*)d_in[6];
    const float* w2 = (const float*)d_in[7];
    const float* g2 = (const float*)d_in[8];
    const float* b2 = (const float*)d_in[9];
    const float* fw = (const float*)d_in[10];
    const float* fb = (const float*)d_in[11];
    float* outv = (float*)d_out;
    char* ws = (char*)d_ws;

    float*     ss    = (float*)(ws + 1024);
    uint16_t*  w1f   = (uint16_t*)(ws + 2048);
    float*     w2s   = (float*)(ws + 38912);
    float*     p0    = (float*)(ws + 76800);
    float*     p1    = (float*)(ws + 76800);
    uint32_t*  s1    = (uint32_t*)(ws + 25766912);
    float*     hp1   = (float*)(ws + 32582656);
    float*     p2    = (float*)(ws + 37301248);
    double*    part1 = (double*)(ws + 60000000);
    int8_t*    s0    = (int8_t*)(ws + 102837248);
    double*    part0 = (double*)(ws + 102837248);
    double*    part2 = (double*)(ws + 102837248);
    float*     hp0   = (float*)(ws + 128527360);

    k_signw1<<<36, 256, 0, stream>>>(w1, w1f);
    k_signw<<<36, 256, 0, stream>>>(w2, w2s);

    k_conv0<<<BATCH, 256, 0, stream>>>(x, w0, p0, part0);
    k_finalize<<<32, 256, 0, stream>>>(part0, 4096, g0, b0, 1.0 / (BATCH * 196.0), ss);
    k_bn0<<<BATCH, 256, 0, stream>>>(p0, ss, s0, hp0);

    k_conv1m<<<BATCH / 4, 256, 0, stream>>>(s0, w1f, p1, part1);
    k_finalize<<<32, 256, 0, stream>>>(part1, 1024, g1, b1, 1.0 / (BATCH * 49.0), ss + 64);
    k_bn1<<<BATCH, 256, 0, stream>>>(p1, hp0, ss, s1, hp1);

    k_conv2<<<(BATCH + 4) / 5, 256, 0, stream>>>(s1, w2s, p2, BATCH);
    k_stats2p<<<256, 256, 0, stream>>>(p2, part2);
    k_finalize<<<32, 256, 0, stream>>>(part2, 256, g2, b2, 1.0 / (BATCH * 9.0), ss + 128);

    k_fc<<<BATCH / 4, 256, 0, stream>>>(p2, hp1, ss, fw, fb, outv);
}

// Round 7
// 236.893 us; speedup vs baseline: 2.7507x; 1.3014x over previous
//
#include <hip/hip_runtime.h>
#include <stdint.h>

#define BATCH 4096

typedef float v16f __attribute__((ext_vector_type(16)));
typedef short v8s  __attribute__((ext_vector_type(8)));

__device__ __forceinline__ int sgn8(float v) {
    return (v > 0.f) ? 1 : ((v < 0.f) ? -1 : 0);
}

// ---------------------------------------------------------------------------
// sign(w) -> bf16 MFMA B-fragment layout (used for BOTH w1 and w2):
// o[tp*1024 + kh*512 + q*256 + n*8 + j] = sign(w[n][kh*16+q*8+j][tp]) as bf16
// ---------------------------------------------------------------------------
__global__ void k_signw1(const float* __restrict__ w, uint16_t* __restrict__ o) {
    int i = blockIdx.x * 256 + threadIdx.x;
    if (i >= 9216) return;
    int j = i & 7, n = (i >> 3) & 31, q = (i >> 8) & 1, kh = (i >> 9) & 1, tp = i >> 10;
    int cin = kh * 16 + q * 8 + j;
    float v = w[(n * 32 + cin) * 9 + tp];
    o[i] = (v > 0.f) ? 0x3F80 : ((v < 0.f) ? 0xBF80 : 0);
}

// ---------------------------------------------------------------------------
// conv0: fp32 1->32ch 3x3 pad1 on 28x28 + maxpool2 -> p0 [B][32][14][14],
// WITH fused per-channel double stats (thread owns channel c=t>>3).
// ---------------------------------------------------------------------------
__global__ __launch_bounds__(256) void k_conv0(const float* __restrict__ x,
                                               const float* __restrict__ w0,
                                               float* __restrict__ p0,
                                               double* __restrict__ part0) {
    __shared__ float xs[900];   // 30x30 halo
    __shared__ float wl[288];
    __shared__ double rs[32][8], rq[32][8];
    int n = blockIdx.x, t = threadIdx.x;
    for (int i = t; i < 900; i += 256) xs[i] = 0.f;
    __syncthreads();
    for (int i = t; i < 784; i += 256) {
        int y = i / 28, xx = i - y * 28;
        xs[(y + 1) * 30 + xx + 1] = x[n * 784 + i];
    }
    for (int i = t; i < 288; i += 256) wl[i] = w0[i];
    __syncthreads();
    int c = t >> 3, j = t & 7;
    const float* wp = &wl[c * 9];
    double s = 0.0, q = 0.0;
    for (int pix = j; pix < 196; pix += 8) {
        int py = pix / 14, px = pix - py * 14;
        float a[4][4];
        #pragma unroll
        for (int r = 0; r < 4; ++r) {
            const float2* ar = (const float2*)&xs[(2 * py + r) * 30 + 2 * px];
            float2 lo = ar[0], hi = ar[1];
            a[r][0] = lo.x; a[r][1] = lo.y; a[r][2] = hi.x; a[r][3] = hi.y;
        }
        float m = -3.4e38f;
        #pragma unroll
        for (int dy = 0; dy < 2; ++dy)
        #pragma unroll
        for (int dx = 0; dx < 2; ++dx) {
            float sum = 0.f;
            #pragma unroll
            for (int ky = 0; ky < 3; ++ky)
            #pragma unroll
            for (int kx = 0; kx < 3; ++kx)
                sum = fmaf(a[dy + ky][dx + kx], wp[ky * 3 + kx], sum);
            m = fmaxf(m, sum);
        }
        p0[n * 6272 + c * 196 + pix] = m;
        double v = (double)m;
        s += v; q += v * v;
    }
    rs[c][j] = s; rq[c][j] = q;
    __syncthreads();
    if (t < 32) {
        double S = 0.0, Q = 0.0;
        #pragma unroll
        for (int i = 0; i < 8; ++i) { S += rs[t][i]; Q += rq[t][i]; }
        part0[n * 32 + t] = S;
        part0[4096 * 32 + n * 32 + t] = Q;
    }
}

// ---------------------------------------------------------------------------
// finalize: grid(32) x 256 threads. Block = channel. Fixed-order reduction
// of G partials (layout part[i*32+c]); double math; deterministic.
// ---------------------------------------------------------------------------
__global__ __launch_bounds__(256) void k_finalize(const double* __restrict__ part, int G,
                                                  const float* __restrict__ g,
                                                  const float* __restrict__ b,
                                                  double inv_count, float* __restrict__ ss) {
    int c = blockIdx.x, t = threadIdx.x;
    double s = 0.0, q = 0.0;
    for (int i = t; i < G; i += 256) {
        s += part[i * 32 + c];
        q += part[G * 32 + i * 32 + c];
    }
    #pragma unroll
    for (int o = 32; o > 0; o >>= 1) { s += __shfl_down(s, o); q += __shfl_down(q, o); }
    __shared__ double rs[4], rq[4];
    int w = t >> 6, l = t & 63;
    if (l == 0) { rs[w] = s; rq[w] = q; }
    __syncthreads();
    if (t == 0) {
        s = rs[0] + rs[1] + rs[2] + rs[3];
        q = rq[0] + rq[1] + rq[2] + rq[3];
        double mean = s * inv_count;
        double var = q * inv_count - mean * mean;
        double sc = (double)g[c] / sqrt(var + 1e-5);
        ss[c] = (float)sc;
        ss[32 + c] = (float)((double)b[c] - mean * sc);
    }
}

// ---------------------------------------------------------------------------
// bn0: block per image. p0 NCHW staged in LDS; writes s0 NHWC int8
// [n][196][32] and hp0 NHWC fp32 [n][49][32].
// ---------------------------------------------------------------------------
__global__ __launch_bounds__(256) void k_bn0(const float* __restrict__ p0,
                                             const float* __restrict__ ss,
                                             int8_t* __restrict__ s0,
                                             float* __restrict__ hp0) {
    __shared__ float P[6272];
    int n = blockIdx.x, t = threadIdx.x;
    const float* src = p0 + n * 6272;
    for (int i = t; i < 6272; i += 256) P[i] = src[i];
    __syncthreads();
    if (t < 196) {
        int p = t;
        uint32_t pk[8];
        #pragma unroll
        for (int cg = 0; cg < 8; ++cg) {
            uint32_t u = 0;
            #pragma unroll
            for (int k = 0; k < 4; ++k) {
                int c = cg * 4 + k;
                float v = fmaf(ss[c], P[c * 196 + p], ss[32 + c]);
                u |= ((uint32_t)(uint8_t)(int8_t)sgn8(v)) << (8 * k);
            }
            pk[cg] = u;
        }
        uint4* dst = (uint4*)(s0 + (size_t)n * 6272 + p * 32);
        uint4 v0; v0.x = pk[0]; v0.y = pk[1]; v0.z = pk[2]; v0.w = pk[3];
        uint4 v1; v1.x = pk[4]; v1.y = pk[5]; v1.z = pk[6]; v1.w = pk[7];
        dst[0] = v0; dst[1] = v1;

        int pw = t >> 2, oct = t & 3;           // 49 pw x 4 octs = 196
        int py = pw / 7, px = pw - py * 7;
        float out[8];
        #pragma unroll
        for (int k = 0; k < 8; ++k) {
            int c = oct * 8 + k;
            float sc = ss[c], sh = ss[32 + c];
            const float* B = &P[c * 196];
            float a0 = fmaf(sc, B[(2 * py) * 14 + 2 * px], sh);
            float a1 = fmaf(sc, B[(2 * py) * 14 + 2 * px + 1], sh);
            float a2 = fmaf(sc, B[(2 * py + 1) * 14 + 2 * px], sh);
            float a3 = fmaf(sc, B[(2 * py + 1) * 14 + 2 * px + 1], sh);
            out[k] = fmaxf(fmaxf(a0, a1), fmaxf(a2, a3));
        }
        float4* hd = (float4*)(hp0 + ((size_t)n * 49 + pw) * 32 + oct * 8);
        float4 h0; h0.x = out[0]; h0.y = out[1]; h0.z = out[2]; h0.w = out[3];
        float4 h1; h1.x = out[4]; h1.y = out[5]; h1.z = out[6]; h1.w = out[7];
        hd[0] = h0; hd[1] = h1;
    }
}

// ---------------------------------------------------------------------------
// conv1 bf16 MFMA implicit GEMM, 4 images/block, fused stats (G=1024).
// ---------------------------------------------------------------------------
__global__ __launch_bounds__(256) void k_conv1m(const int8_t* __restrict__ s0,
                                                const uint16_t* __restrict__ w1f,
                                                float* __restrict__ p1,
                                                double* __restrict__ part1) {
    __shared__ uint32_t lds[16384];   // 64 KB: 4 images x 256 pixels x 16 dwords
    int t = threadIdx.x;
    int n0 = blockIdx.x * 4;
    if (t < 240) {
        int img = t / 60, e = t % 60;
        int yh, xh;
        if (e < 16)      { yh = 0;      xh = e; }
        else if (e < 32) { yh = 15;     xh = e - 16; }
        else if (e < 46) { yh = e - 31; xh = 0; }
        else             { yh = e - 45; xh = 15; }
        uint32_t* d = &lds[img * 4096 + (yh * 16 + xh) * 16];
        uint4 z; z.x = z.y = z.z = z.w = 0u;
        ((uint4*)d)[0] = z; ((uint4*)d)[1] = z; ((uint4*)d)[2] = z; ((uint4*)d)[3] = z;
    }
    int lane = t & 63, wv = t >> 6;
    int q = lane >> 5, ncol = lane & 31;
    v8s wfr[18];
    #pragma unroll
    for (int f = 0; f < 18; ++f)
        wfr[f] = *(const v8s*)(w1f + (f * 2 + q) * 256 + ncol * 8);
    for (int i = t; i < 6272; i += 256) {
        int img = i / 1568, r = i - img * 1568;
        int pimg = r >> 3, dp = r & 7;
        int iy = pimg / 14, ix = pimg - iy * 14;
        int p = (iy + 1) * 16 + ix + 1;
        uint32_t u = ((const uint32_t*)s0)[(size_t)(n0 + img) * 1568 + r];
        uint32_t b0 = u & 0xFF, b1 = (u >> 8) & 0xFF, b2 = (u >> 16) & 0xFF, b3 = u >> 24;
        uint32_t h0 = b0 ? (0x3F80u | ((b0 & 0x80u) << 8)) : 0u;
        uint32_t h1 = b1 ? (0x3F80u | ((b1 & 0x80u) << 8)) : 0u;
        uint32_t h2 = b2 ? (0x3F80u | ((b2 & 0x80u) << 8)) : 0u;
        uint32_t h3 = b3 ? (0x3F80u | ((b3 & 0x80u) << 8)) : 0u;
        int g = dp >> 1;
        int gs = g ^ (p & 3);
        int idx = img * 4096 + p * 16 + (gs << 2) + ((dp & 1) << 1);
        lds[idx] = h0 | (h1 << 16);
        lds[idx + 1] = h2 | (h3 << 16);
    }
    __syncthreads();
    int n = n0 + wv;
    int ibase = wv * 4096;
    int m = lane & 31;
    int quad = m & 3, pwl = m >> 2;
    int dy = quad >> 1, dx = quad & 1;
    double sAcc = 0.0, qAcc = 0.0;
    for (int tile = 0; tile < 7; ++tile) {
        int pw = tile * 8 + pwl;
        int pwc = min(pw, 48);
        int py = pwc / 7, px = pwc - py * 7;
        int pbase = (2 * py + dy) * 16 + 2 * px + dx;
        v16f acc;
        #pragma unroll
        for (int i = 0; i < 16; ++i) acc[i] = 0.f;
        #pragma unroll
        for (int tp = 0; tp < 9; ++tp) {
            int p = pbase + (tp / 3) * 16 + (tp % 3);
            int psw = p & 3;
            #pragma unroll
            for (int kh = 0; kh < 2; ++kh) {
                int g = kh * 2 + q;
                int idx = ibase + p * 16 + ((g ^ psw) << 2);
                v8s a = *(const v8s*)&lds[idx];
                acc = __builtin_amdgcn_mfma_f32_32x32x16_bf16(a, wfr[tp * 2 + kh], acc, 0, 0, 0);
            }
        }
        #pragma unroll
        for (int g4 = 0; g4 < 4; ++g4) {
            float mx = fmaxf(fmaxf(acc[4 * g4], acc[4 * g4 + 1]),
                             fmaxf(acc[4 * g4 + 2], acc[4 * g4 + 3]));
            int pwo = tile * 8 + 2 * g4 + q;
            if (pwo < 49) {
                p1[((size_t)n * 49 + pwo) * 32 + ncol] = mx;
                double v = (double)mx;
                sAcc += v; qAcc += v * v;
            }
        }
    }
    __syncthreads();
    double* red = (double*)lds;   // act LDS dead; 512 doubles used
    red[(wv * 2 + q) * 32 + ncol] = sAcc;
    red[256 + (wv * 2 + q) * 32 + ncol] = qAcc;
    __syncthreads();
    if (t < 32) {
        double S = 0.0, Q = 0.0;
        #pragma unroll
        for (int i = 0; i < 8; ++i) { S += red[i * 32 + t]; Q += red[256 + i * 32 + t]; }
        part1[blockIdx.x * 32 + t] = S;
        part1[1024 * 32 + blockIdx.x * 32 + t] = Q;
    }
}

// ---------------------------------------------------------------------------
// bn1: block per image. h = bn1(p1) + hp0 (both NHWC) in LDS; emits
// s1 NCHW-packed (for conv2m) and hp1 NCHW [n][c][9] (for FC).
// s1 image stride = 416 WORDS (32 ch x 13 words).
// ---------------------------------------------------------------------------
__global__ __launch_bounds__(256) void k_bn1(const float* __restrict__ p1,
                                             const float* __restrict__ hp0,
                                             const float* __restrict__ ss,
                                             uint32_t* __restrict__ s1,
                                             float* __restrict__ hp1) {
    __shared__ float H[1568];
    int n = blockIdx.x, t = threadIdx.x;
    const float* P = p1 + (size_t)n * 1568;
    const float* Hp = hp0 + (size_t)n * 1568;
    for (int i = t; i < 1568; i += 256) {
        int c = i & 31;
        H[i] = fmaf(ss[64 + c], P[i], ss[96 + c]) + Hp[i];
    }
    __syncthreads();
    if (t < 32) {
        int c = t;
        uint32_t* sp = s1 + (size_t)n * 416 + c * 13;
        for (int j = 0; j < 13; ++j) {
            uint32_t u = 0;
            #pragma unroll
            for (int k = 0; k < 4; ++k) {
                int f = 4 * j + k;
                int sv = (f < 49) ? sgn8(H[f * 32 + c]) : 0;
                u |= ((uint32_t)(uint8_t)(int8_t)sv) << (8 * k);
            }
            sp[j] = u;
        }
    }
    for (int jj = t; jj < 288; jj += 256) {
        int c = jj / 9, pix = jj - c * 9;
        int r = pix / 3, qq = pix - r * 3;
        float a0 = H[((2 * r) * 7 + 2 * qq) * 32 + c];
        float a1 = H[((2 * r) * 7 + 2 * qq + 1) * 32 + c];
        float a2 = H[((2 * r + 1) * 7 + 2 * qq) * 32 + c];
        float a3 = H[((2 * r + 1) * 7 + 2 * qq + 1) * 32 + c];
        hp1[n * 288 + c * 9 + pix] = fmaxf(fmaxf(a0, a1), fmaxf(a2, a3));
    }
}

// ---------------------------------------------------------------------------
// conv2 via bf16 MFMA implicit GEMM + fused stats. 8 images/block.
// LDS act per image: 8x8 halo grid (rows/cols -1..6) x 32ch bf16, swizzled
// like conv1m (1024 dwords = 4KB per image, 32 KB total).
// M = 8img x 9pw x 4quad = 288 rows = exactly 9 tiles of 32 (no bounds).
// Wave wv handles tiles wv, wv+4, wv+8. In-register 2x2 maxpool; fused
// per-channel double stats -> part2[b*32+c], G=512. p2 NCHW [n][32][9].
// s1 image stride = 416 WORDS.
// ---------------------------------------------------------------------------
__global__ __launch_bounds__(256) void k_conv2m(const uint32_t* __restrict__ s1,
                                                const uint16_t* __restrict__ w2f,
                                                float* __restrict__ p2,
                                                double* __restrict__ part2) {
    __shared__ uint32_t lds[8192];   // 32 KB
    int t = threadIdx.x;
    int n0 = blockIdx.x * 8;
    // zero pad pixels: row 0 and col 0 of each 8x8 halo grid (15/image)
    for (int i = t; i < 120; i += 256) {
        int img = i / 15, e = i - img * 15;
        int p = (e < 8) ? e : (e - 7) * 8;
        uint32_t* d = &lds[img * 1024 + p * 16];
        uint4 z; z.x = z.y = z.z = z.w = 0u;
        ((uint4*)d)[0] = z; ((uint4*)d)[1] = z; ((uint4*)d)[2] = z; ((uint4*)d)[3] = z;
    }
    int lane = t & 63, wv = t >> 6;
    int q = lane >> 5, ncol = lane & 31;
    v8s wfr[18];
    #pragma unroll
    for (int f = 0; f < 18; ++f)
        wfr[f] = *(const v8s*)(w2f + (f * 2 + q) * 256 + ncol * 8);
    // stage: 8 img x 16 cin-pairs x 13 packed words
    for (int i = t; i < 1664; i += 256) {
        int img = i / 208, r = i - img * 208;
        int c2 = r / 13, j = r - c2 * 13;
        const uint32_t* sb = s1 + (size_t)(n0 + img) * 416;
        uint32_t wa = sb[(2 * c2) * 13 + j];
        uint32_t wb = sb[(2 * c2 + 1) * 13 + j];
        int g = c2 >> 2, sub = c2 & 3;
        #pragma unroll
        for (int k = 0; k < 4; ++k) {
            int f = 4 * j + k;
            if (f < 49) {
                int y = f / 7, x = f - y * 7;
                int p = (y + 1) * 8 + (x + 1);
                uint32_t ba = (wa >> (8 * k)) & 0xFF;
                uint32_t bb = (wb >> (8 * k)) & 0xFF;
                uint32_t ha = ba ? (0x3F80u | ((ba & 0x80u) << 8)) : 0u;
                uint32_t hb = bb ? (0x3F80u | ((bb & 0x80u) << 8)) : 0u;
                lds[img * 1024 + p * 16 + ((g ^ (p & 3)) << 2) + sub] = ha | (hb << 16);
            }
        }
    }
    __syncthreads();
    int m = lane & 31;
    int quad = m & 3, pwl = m >> 2;
    int dy = quad >> 1, dx = quad & 1;
    double sAcc = 0.0, qAcc = 0.0;
    for (int tile = wv; tile < 9; tile += 4) {
        int pwg = tile * 8 + pwl;                    // 0..71
        int img = pwg / 9, pwi = pwg - img * 9;
        int py = pwi / 3, px = pwi - py * 3;
        int pbase = (2 * py + dy) * 8 + 2 * px + dx;
        v16f acc;
        #pragma unroll
        for (int i = 0; i < 16; ++i) acc[i] = 0.f;
        #pragma unroll
        for (int tp = 0; tp < 9; ++tp) {
            int p = pbase + (tp / 3) * 8 + (tp % 3);
            int psw = p & 3;
            #pragma unroll
            for (int kh = 0; kh < 2; ++kh) {
                int g = kh * 2 + q;
                int idx = img * 1024 + p * 16 + ((g ^ psw) << 2);
                v8s a = *(const v8s*)&lds[idx];
                acc = __builtin_amdgcn_mfma_f32_32x32x16_bf16(a, wfr[tp * 2 + kh], acc, 0, 0, 0);
            }
        }
        #pragma unroll
        for (int g4 = 0; g4 < 4; ++g4) {
            float mx = fmaxf(fmaxf(acc[4 * g4], acc[4 * g4 + 1]),
                             fmaxf(acc[4 * g4 + 2], acc[4 * g4 + 3]));
            int pwo = tile * 8 + 2 * g4 + q;          // 0..71
            int oimg = pwo / 9, opwi = pwo - oimg * 9;
            p2[(size_t)(n0 + oimg) * 288 + ncol * 9 + opwi] = mx;
            double v = (double)mx;
            sAcc += v; qAcc += v * v;
        }
    }
    __syncthreads();
    double* red = (double*)lds;   // act LDS dead; 512 doubles
    red[(wv * 2 + q) * 32 + ncol] = sAcc;
    red[256 + (wv * 2 + q) * 32 + ncol] = qAcc;
    __syncthreads();
    if (t < 32) {
        double S = 0.0, Q = 0.0;
        #pragma unroll
        for (int i = 0; i < 8; ++i) { S += red[i * 32 + t]; Q += red[256 + i * 32 + t]; }
        part2[blockIdx.x * 32 + t] = S;
        part2[512 * 32 + blockIdx.x * 32 + t] = Q;
    }
}

// ---------------------------------------------------------------------------
// FC: out[n,k] = sum_j (bn2(p2)+hp1)[n,j] * fw[k,j] + fb[k].  Wave per image.
// ---------------------------------------------------------------------------
__global__ __launch_bounds__(256) void k_fc(const float* __restrict__ p2,
                                            const float* __restrict__ hp1,
                                            const float* __restrict__ ss,
                                            const float* __restrict__ fw,
                                            const float* __restrict__ fb,
                                            float* __restrict__ outv) {
    int wv = threadIdx.x >> 6, l = threadIdx.x & 63;
    int n = blockIdx.x * 4 + wv;
    float acc[10];
    #pragma unroll
    for (int k = 0; k < 10; ++k) acc[k] = 0.f;
    #pragma unroll
    for (int i = 0; i < 5; ++i) {
        int j = l + 64 * i;
        if (j < 288) {
            int c = j / 9;
            float h = fmaf(ss[128 + c], p2[n * 288 + j], ss[160 + c]) + hp1[n * 288 + j];
            #pragma unroll
            for (int k = 0; k < 10; ++k)
                acc[k] = fmaf(h, fw[k * 288 + j], acc[k]);
        }
    }
    #pragma unroll
    for (int k = 0; k < 10; ++k) {
        float s = acc[k];
        #pragma unroll
        for (int o = 32; o > 0; o >>= 1) s += __shfl_down(s, o);
        if (l == 0) outv[n * 10 + k] = s + fb[k];
    }
}

// ---------------------------------------------------------------------------
// Workspace layout (bytes), ~154.2 MB.
//   ss   @1024  768 | w1f @2048 18432(bf16) | w2f @38912 18432(bf16)
//   p0   @76800 102760448 | p1(NHWC) @76800 25690112
//   s1   @25766912 (416 words/img) | hp1 @32582656 | p2 @37301248
//   part1 @60000000 512KB  (dead mid-p0 zone during conv1m->finalize1)
//   s0(NHWC int8) @102837248 25690112
//     part0 (2 MB, conv0->finalize0, before bn0 writes s0) aliases its head
//     part2 (256 KB, conv2m->finalize2, s0 long dead) aliases its head
//   hp0(NHWC) @128527360 25690112
// ---------------------------------------------------------------------------
extern "C" void kernel_launch(void* const* d_in, const int* in_sizes, int n_in,
                              void* d_out, int out_size, void* d_ws, size_t ws_size,
                              hipStream_t stream) {
    (void)in_sizes; (void)n_in; (void)out_size; (void)ws_size;
    const float* x  = (const float*)d_in[0];
    const float* w0 = (const float*)d_in[1];
    const float* g0 = (const float*)d_in[2];
    const float* b0 = (const float*)d_in[3];
    const float* w1 = (const float*)d_in[4];
    const float* g1 = (const float*)d_in[5];
    const float* b1 = (const float*)d_in[6];
    const float* w2 = (const float*)d_in[7];
    const float* g2 = (const float*)d_in[8];
    const float* b2 = (const float*)d_in[9];
    const float* fw = (const float*)d_in[10];
    const float* fb = (const float*)d_in[11];
    float* outv = (float*)d_out;
    char* ws = (char*)d_ws;

    float*     ss    = (float*)(ws + 1024);
    uint16_t*  w1f   = (uint16_t*)(ws + 2048);
    uint16_t*  w2f   = (uint16_t*)(ws + 38912);
    float*     p0    = (float*)(ws + 76800);
    float*     p1    = (float*)(ws + 76800);
    uint32_t*  s1    = (uint32_t*)(ws + 25766912);
    float*     hp1   = (float*)(ws + 32582656);
    float*     p2    = (float*)(ws + 37301248);
    double*    part1 = (double*)(ws + 60000000);
    int8_t*    s0    = (int8_t*)(ws + 102837248);
    double*    part0 = (double*)(ws + 102837248);
    double*    part2 = (double*)(ws + 102837248);
    float*     hp0   = (float*)(ws + 128527360);

    k_signw1<<<36, 256, 0, stream>>>(w1, w1f);
    k_signw1<<<36, 256, 0, stream>>>(w2, w2f);

    k_conv0<<<BATCH, 256, 0, stream>>>(x, w0, p0, part0);
    k_finalize<<<32, 256, 0, stream>>>(part0, 4096, g0, b0, 1.0 / (BATCH * 196.0), ss);
    k_bn0<<<BATCH, 256, 0, stream>>>(p0, ss, s0, hp0);

    k_conv1m<<<BATCH / 4, 256, 0, stream>>>(s0, w1f, p1, part1);
    k_finalize<<<32, 256, 0, stream>>>(part1, 1024, g1, b1, 1.0 / (BATCH * 49.0), ss + 64);
    k_bn1<<<BATCH, 256, 0, stream>>>(p1, hp0, ss, s1, hp1);

    k_conv2m<<<BATCH / 8, 256, 0, stream>>>(s1, w2f, p2, part2);
    k_finalize<<<32, 256, 0, stream>>>(part2, 512, g2, b2, 1.0 / (BATCH * 9.0), ss + 128);

    k_fc<<<BATCH / 4, 256, 0, stream>>>(p2, hp1, ss, fw, fb, outv);
}